// Round 2
// baseline (315.340 us; speedup 1.0000x reference)
//
#include <hip/hip_runtime.h>
#include <stdint.h>

// Problem constants (fixed by reference setup_inputs)
#define CIN   256
#define COUT  256
#define Hdim  56
#define Wdim  56
#define HW    3136        // 56*56
#define BATCH 32
#define NPIX  100352      // 32*3136
#define KREP  589824      // 256*256*9, stride between weight replicas
#define TAPS  9
#define WORDS 8           // 8 x uint32 = 256 channel bits

// ws layout (bytes)
#define OFF_WPACK 0         // 256*72*4   = 73728
#define OFF_FTAB  73728     // 9*256*4    = 9216   (F = 256*ntap + 2*corr)
#define OFF_SA    82944     // 256*4      = 1024
#define OFF_XBITS 84224     // 100352*8*4 = 3211264   (16B aligned)

// ---------------------------------------------------------------------------
// P1: build real_w = sum_k RV[k]*W[k], pack sign bits per (co, tap, word),
//     compute sa[co] = mean|real_w| * alpha[co], and the folded border table
//     F[pattern][co] = 256*ntap(pattern) + 2*corr, where corr = sum of
//     popc(wbits) over taps that fall outside the image for that pattern.
// One block per co, 256 threads.
// ---------------------------------------------------------------------------
__global__ __launch_bounds__(256) void prep_w_kernel(
    const float* __restrict__ wts, const float* __restrict__ RV,
    const float* __restrict__ alpha, uint32_t* __restrict__ wpack,
    uint32_t* __restrict__ Ftab, float* __restrict__ sa)
{
    __shared__ uint32_t bits[TAPS * WORDS];   // 72 words
    __shared__ float    red[256];
    __shared__ int      pcw[TAPS];

    const int co = blockIdx.x;
    const int t  = threadIdx.x;

    if (t < TAPS * WORDS) bits[t] = 0u;
    __syncthreads();

    const float r0 = RV[0], r1 = RV[1], r2 = RV[2], r3 = RV[3];
    const float* base = wts + (size_t)co * 2304;

    float acc = 0.f;
#pragma unroll
    for (int j = 0; j < 9; ++j) {
        const int e = j * 256 + t;              // 0..2303, e = ci*9 + tap
        const float w0 = base[e];
        const float w1 = base[e + KREP];
        const float w2 = base[e + 2 * KREP];
        const float w3 = base[e + 3 * KREP];
        const float rw = r0 * w0 + r1 * w1 + r2 * w2 + r3 * w3;
        acc += fabsf(rw);
        const int ci  = e / 9;
        const int tap = e - ci * 9;
        if (rw < 0.f)
            atomicOr(&bits[tap * WORDS + (ci >> 5)], 1u << (ci & 31));
    }
    red[t] = acc;
    __syncthreads();

    for (int s = 128; s > 0; s >>= 1) {
        if (t < s) red[t] += red[t + s];
        __syncthreads();
    }

    if (t == 0) {
        const float scale = red[0] * (1.0f / 2304.0f);
        sa[co] = scale * alpha[co];
    }
    if (t < TAPS * WORDS) wpack[co * 72 + t] = bits[t];
    if (t < TAPS) {
        int s = 0;
#pragma unroll
        for (int wd = 0; wd < WORDS; ++wd) s += __popc(bits[t * WORDS + wd]);
        pcw[t] = s;
    }
    __syncthreads();
    if (t < TAPS) {
        const int vp = t / 3, hp = t % 3;   // pattern id: vp*3+hp
        int c = 0;
#pragma unroll
        for (int kh = 0; kh < 3; ++kh)
#pragma unroll
            for (int kw = 0; kw < 3; ++kw) {
                const bool inv = (vp == 0 && kh == 0) || (vp == 2 && kh == 2) ||
                                 (hp == 0 && kw == 0) || (hp == 2 && kw == 2);
                if (inv) c += pcw[kh * 3 + kw];
            }
        const int ntap = ((vp == 1) ? 3 : 2) * ((hp == 1) ? 3 : 2);
        Ftab[t * 256 + co] = (uint32_t)(256 * ntap + 2 * c);
    }
}

// ---------------------------------------------------------------------------
// P2: binarize+pack x: xbits[pixel][8 words], bit ci = signbit(x[b,ci,h,w]).
// One thread per pixel; per-iteration loads are wave-coalesced (consecutive hw).
// ---------------------------------------------------------------------------
__global__ __launch_bounds__(256) void pack_x_kernel(
    const float* __restrict__ x, uint32_t* __restrict__ xbits)
{
    const int p  = blockIdx.x * 256 + threadIdx.x;   // pixel id < NPIX
    const int b  = p / HW;
    const int hw = p - b * HW;
    const float* xp = x + (size_t)b * CIN * HW + hw;

    uint32_t wv[WORDS];
#pragma unroll
    for (int j = 0; j < WORDS; ++j) {
        uint32_t m = 0;
#pragma unroll
        for (int bit = 0; bit < 32; ++bit) {
            const float v = xp[(size_t)(j * 32 + bit) * HW];
            m |= (__float_as_uint(v) >> 31) << bit;   // sign bit
        }
        wv[j] = m;
    }
    uint4* dst = (uint4*)(xbits + (size_t)p * WORDS);
    dst[0] = make_uint4(wv[0], wv[1], wv[2], wv[3]);
    dst[1] = make_uint4(wv[4], wv[5], wv[6], wv[7]);
}

// ---------------------------------------------------------------------------
// C: XNOR-popcount conv, v2: weights read via wave-uniform SCALAR loads
// (address is uniform: arg-pointer + blockIdx/loop offsets; all pointers
// const __restrict__ so the loads are invariant -> SMEM). x bits live in
// VGPRs; the inner op is v_xor_b32 v,s,v + accumulating v_bcnt_u32_b32.
// Grid = 392 pixel-blocks x 2 co-chunks. LDS only holds the tiny F/sa tables.
// ---------------------------------------------------------------------------
__global__ __launch_bounds__(256) void conv_xnor_kernel(
    const uint32_t* __restrict__ xbits, const uint32_t* __restrict__ wpack,
    const uint32_t* __restrict__ Ftab, const float* __restrict__ sa_g,
    float* __restrict__ out)
{
    __shared__ uint32_t F_s[9 * 257];   // stride 257 splits patterns across banks
    __shared__ float    sa_s[COUT];

    const int tid = threadIdx.x;
    const int pb  = blockIdx.x >> 1;      // pixel block
    const int ch  = blockIdx.x & 1;       // co chunk (0/1)

    const int p  = pb * 256 + tid;
    const int b  = p / HW;
    const int hw = p - b * HW;
    const int h  = hw / Wdim;
    const int w  = hw - h * Wdim;

#pragma unroll
    for (int j = 0; j < 9; ++j) F_s[j * 257 + tid] = Ftab[j * 256 + tid];
    sa_s[tid] = sa_g[tid];

    // border pattern
    const int vp  = (h == 0) ? 0 : ((h == Hdim - 1) ? 2 : 1);
    const int hp  = (w == 0) ? 0 : ((w == Wdim - 1) ? 2 : 1);
    const int pat = vp * 3 + hp;

    // load x bits for the 9 taps (invalid taps -> 0)
    uint32_t xq[72];
#pragma unroll
    for (int kh = 0; kh < 3; ++kh)
#pragma unroll
        for (int kw = 0; kw < 3; ++kw) {
            const int t  = kh * 3 + kw;
            const int hh = h + kh - 1, ww = w + kw - 1;
            if (hh >= 0 && hh < Hdim && ww >= 0 && ww < Wdim) {
                const uint4* src =
                    (const uint4*)(xbits + (size_t)(b * HW + hh * Wdim + ww) * WORDS);
                const uint4 a = src[0], c = src[1];
                xq[t * 8 + 0] = a.x; xq[t * 8 + 1] = a.y;
                xq[t * 8 + 2] = a.z; xq[t * 8 + 3] = a.w;
                xq[t * 8 + 4] = c.x; xq[t * 8 + 5] = c.y;
                xq[t * 8 + 6] = c.z; xq[t * 8 + 7] = c.w;
            } else {
#pragma unroll
                for (int j = 0; j < 8; ++j) xq[t * 8 + j] = 0u;
            }
        }

    __syncthreads();

    float* outp = out + (size_t)b * COUT * HW + hw;
    const uint32_t* __restrict__ wbase = wpack + (size_t)ch * 128 * 72;

#pragma unroll 2
    for (int col = 0; col < 128; ++col) {
        const int co = ch * 128 + col;
        const uint32_t* __restrict__ wp = wbase + col * 72;   // uniform address
        int m0 = 0, m1 = 0, m2 = 0, m3 = 0;
#pragma unroll
        for (int q = 0; q < 18; ++q) {
            m0 += __popc(xq[q * 4 + 0] ^ wp[q * 4 + 0]);
            m1 += __popc(xq[q * 4 + 1] ^ wp[q * 4 + 1]);
            m2 += __popc(xq[q * 4 + 2] ^ wp[q * 4 + 2]);
            m3 += __popc(xq[q * 4 + 3] ^ wp[q * 4 + 3]);
        }
        const int mm = (m0 + m1) + (m2 + m3);
        const int F  = (int)F_s[pat * 257 + co];
        outp[(size_t)co * HW] = sa_s[co] * (float)(F - 2 * mm);
    }
}

extern "C" void kernel_launch(void* const* d_in, const int* in_sizes, int n_in,
                              void* d_out, int out_size, void* d_ws, size_t ws_size,
                              hipStream_t stream) {
    const float* x     = (const float*)d_in[0];   // [32,256,56,56]
    const float* wts   = (const float*)d_in[1];   // [4,256,256,3,3]
    const float* RV    = (const float*)d_in[2];   // [5]
    const float* alpha = (const float*)d_in[3];   // [256,1,1]
    float* out = (float*)d_out;                   // [32,256,56,56]

    uint8_t* ws = (uint8_t*)d_ws;
    uint32_t* wpack  = (uint32_t*)(ws + OFF_WPACK);
    uint32_t* Ftab   = (uint32_t*)(ws + OFF_FTAB);
    float*    sa     = (float*)   (ws + OFF_SA);
    uint32_t* xbits  = (uint32_t*)(ws + OFF_XBITS);

    prep_w_kernel<<<COUT, 256, 0, stream>>>(wts, RV, alpha, wpack, Ftab, sa);
    pack_x_kernel<<<NPIX / 256, 256, 0, stream>>>(x, xbits);
    conv_xnor_kernel<<<(NPIX / 256) * 2, 256, 0, stream>>>(xbits, wpack, Ftab, sa, out);
}

// Round 4
// 174.346 us; speedup vs baseline: 1.8087x; 1.8087x over previous
//
#include <hip/hip_runtime.h>
#include <stdint.h>

// Problem constants (fixed by reference setup_inputs)
#define CIN   256
#define COUT  256
#define Hdim  56
#define Wdim  56
#define HW    3136        // 56*56
#define BATCH 32
#define NPIX  100352      // 32*3136
#define KREP  589824      // 256*256*9, stride between weight replicas
#define TAPS  9
#define WORDS 8           // 8 x uint32 = 256 channel bits

// ws layout (bytes) — IDENTICAL footprint to the R1/R2 kernels (proven fit)
#define OFF_WPACK 0         // 256*72*4   = 73728
#define OFF_FTAB  73728     // 9*256*4    = 9216   (F = 256*ntap + 2*corr)
#define OFF_SA    82944     // 256*4      = 1024
#define OFF_XBITS 84224     // 100352*8*4 = 3211264 (unpadded [B][56][56][8])

// ---------------------------------------------------------------------------
// P1: real_w = sum_k RV[k]*W[k]; pack sign bits per (co, tap, word);
//     sa[co] = mean|real_w| * alpha[co];
//     Ftab[pattern][co] = 256*ntap + 2*corr (zero-pad-tap correction folded)
// (unchanged from R1/R2 — verified)
// ---------------------------------------------------------------------------
__global__ __launch_bounds__(256) void prep_w_kernel(
    const float* __restrict__ wts, const float* __restrict__ RV,
    const float* __restrict__ alpha, uint32_t* __restrict__ wpack,
    uint32_t* __restrict__ Ftab, float* __restrict__ sa)
{
    __shared__ uint32_t bits[TAPS * WORDS];
    __shared__ float    red[256];
    __shared__ int      pcw[TAPS];

    const int co = blockIdx.x;
    const int t  = threadIdx.x;

    if (t < TAPS * WORDS) bits[t] = 0u;
    __syncthreads();

    const float r0 = RV[0], r1 = RV[1], r2 = RV[2], r3 = RV[3];
    const float* base = wts + (size_t)co * 2304;

    float acc = 0.f;
#pragma unroll
    for (int j = 0; j < 9; ++j) {
        const int e = j * 256 + t;              // e = ci*9 + tap
        const float w0 = base[e];
        const float w1 = base[e + KREP];
        const float w2 = base[e + 2 * KREP];
        const float w3 = base[e + 3 * KREP];
        const float rw = r0 * w0 + r1 * w1 + r2 * w2 + r3 * w3;
        acc += fabsf(rw);
        const int ci  = e / 9;
        const int tap = e - ci * 9;
        if (rw < 0.f)
            atomicOr(&bits[tap * WORDS + (ci >> 5)], 1u << (ci & 31));
    }
    red[t] = acc;
    __syncthreads();

    for (int s = 128; s > 0; s >>= 1) {
        if (t < s) red[t] += red[t + s];
        __syncthreads();
    }

    if (t == 0) sa[co] = (red[0] * (1.0f / 2304.0f)) * alpha[co];
    if (t < TAPS * WORDS) wpack[co * 72 + t] = bits[t];
    if (t < TAPS) {
        int s = 0;
#pragma unroll
        for (int wd = 0; wd < WORDS; ++wd) s += __popc(bits[t * WORDS + wd]);
        pcw[t] = s;
    }
    __syncthreads();
    if (t < TAPS) {
        const int vp = t / 3, hp = t % 3;
        int c = 0;
#pragma unroll
        for (int kh = 0; kh < 3; ++kh)
#pragma unroll
            for (int kw = 0; kw < 3; ++kw) {
                const bool inv = (vp == 0 && kh == 0) || (vp == 2 && kh == 2) ||
                                 (hp == 0 && kw == 0) || (hp == 2 && kw == 2);
                if (inv) c += pcw[kh * 3 + kw];
            }
        const int ntap = ((vp == 1) ? 3 : 2) * ((hp == 1) ? 3 : 2);
        Ftab[t * 256 + co] = (uint32_t)(256 * ntap + 2 * c);
    }
}

// ---------------------------------------------------------------------------
// P2: binarize+pack x (unpadded [B][56][56][8]) — unchanged from R1/R2.
// ---------------------------------------------------------------------------
__global__ __launch_bounds__(256) void pack_x_kernel(
    const float* __restrict__ x, uint32_t* __restrict__ xbits)
{
    const int p  = blockIdx.x * 256 + threadIdx.x;   // pixel id < NPIX
    const int b  = p / HW;
    const int hw = p - b * HW;
    const float* xp = x + (size_t)b * CIN * HW + hw;

    uint32_t wv[WORDS];
#pragma unroll
    for (int j = 0; j < WORDS; ++j) {
        uint32_t m = 0;
#pragma unroll
        for (int bit = 0; bit < 32; ++bit) {
            const float v = xp[(size_t)(j * 32 + bit) * HW];
            m |= (__float_as_uint(v) >> 31) << bit;
        }
        wv[j] = m;
    }
    uint4* dst = (uint4*)(xbits + (size_t)p * WORDS);
    dst[0] = make_uint4(wv[0], wv[1], wv[2], wv[3]);
    dst[1] = make_uint4(wv[4], wv[5], wv[6], wv[7]);
}

// ---------------------------------------------------------------------------
// C: col-resident XNOR conv with sliding x-window.
// Thread = co (256/block); weights resident in 72 VGPRs. Block = 2 output
// rows of one image. The 4 padded input rows are staged in LDS (zero borders
// synthesized here); per pixel only the NEW 3-row column (24 words) is
// broadcast-read (6 ds_read_b128), the rest slides in a 4-slot VGPR window
// (statically rotated, 56 = 4*14). Output via 16-pixel LDS transpose.
// ---------------------------------------------------------------------------
__global__ __launch_bounds__(256, 2) void conv_xnor_kernel(
    const uint32_t* __restrict__ xbits, const uint32_t* __restrict__ wpack,
    const uint32_t* __restrict__ Ftab, const float* __restrict__ sa_g,
    float* __restrict__ out)
{
    __shared__ __align__(16) uint32_t xt[4 * 60 * WORDS];  // 4 rows x 60 cols, 7680 B
    __shared__ float obuf[16 * 258];                       // 16512 B

    const int tid = threadIdx.x;
    const int b   = blockIdx.x / 28;
    const int c   = blockIdx.x - b * 28;
    const int h0  = 2 * c;                 // first output row of this block

    // weights for co=tid -> 18 uint4 (72 VGPRs), resident
    uint4 wqv[18];
    {
        const uint4* src = (const uint4*)(wpack + tid * 72);
#pragma unroll
        for (int i = 0; i < 18; ++i) wqv[i] = src[i];
    }
    const float sa_t = sa_g[tid];

    // stage padded x tile: tile row tr (0..3) = real row h0-1+tr; cols 1..56
    // real, cols 0 and 57..59 zero. dst row stride 120 uint4 (60 cols).
    {
        const uint4* srcb = (const uint4*)(xbits + (size_t)b * HW * WORDS);
        uint4* dst = (uint4*)xt;
        const uint4 z = make_uint4(0u, 0u, 0u, 0u);
#pragma unroll
        for (int rnd = 0; rnd < 2; ++rnd) {
            const int i = tid + rnd * 256;          // dst uint4 index < 480
            if (i < 480) {
                const int tr  = i / 120;
                const int u   = i - tr * 120;
                const int col = u >> 1;             // padded col 0..59
                const int hr  = h0 - 1 + tr;        // real row
                uint4 v = z;
                if (hr >= 0 && hr < Hdim && col >= 1 && col <= Wdim)
                    v = srcb[((size_t)hr * Wdim + (col - 1)) * 2 + (u & 1)];
                dst[i] = v;
            }
        }
    }
    __syncthreads();

    const uint4* xt4 = (const uint4*)xt;
    float* out_b = out + (size_t)b * COUT * HW + (size_t)h0 * Wdim;

    int pslot  = 0;   // running pixel index within block (obuf slot = &15)
    int fcount = 0;   // flushes done

#define LOADSLOT(S, C)                                                       \
    do {                                                                     \
        _Pragma("unroll") for (int r_ = 0; r_ < 3; ++r_) {                   \
            (S)[r_ * 2 + 0] = xt4[(rr + r_) * 120 + (C) * 2 + 0];            \
            (S)[r_ * 2 + 1] = xt4[(rr + r_) * 120 + (C) * 2 + 1];            \
        }                                                                    \
    } while (0)

#define COMPUTE(SA, SB, SC, Wv)                                              \
    do {                                                                     \
        int m0 = 0, m1 = 0, m2 = 0, m3 = 0;                                  \
        _Pragma("unroll") for (int r_ = 0; r_ < 3; ++r_) {                   \
            _Pragma("unroll") for (int q_ = 0; q_ < 2; ++q_) {               \
                const uint4 xa_ = (SA)[r_ * 2 + q_];                         \
                const uint4 wa_ = wqv[(r_ * 3 + 0) * 2 + q_];                \
                m0 += __popc(xa_.x ^ wa_.x); m1 += __popc(xa_.y ^ wa_.y);    \
                m2 += __popc(xa_.z ^ wa_.z); m3 += __popc(xa_.w ^ wa_.w);    \
                const uint4 xb_ = (SB)[r_ * 2 + q_];                         \
                const uint4 wb_ = wqv[(r_ * 3 + 1) * 2 + q_];                \
                m0 += __popc(xb_.x ^ wb_.x); m1 += __popc(xb_.y ^ wb_.y);    \
                m2 += __popc(xb_.z ^ wb_.z); m3 += __popc(xb_.w ^ wb_.w);    \
                const uint4 xc_ = (SC)[r_ * 2 + q_];                         \
                const uint4 wc_ = wqv[(r_ * 3 + 2) * 2 + q_];                \
                m0 += __popc(xc_.x ^ wc_.x); m1 += __popc(xc_.y ^ wc_.y);    \
                m2 += __popc(xc_.z ^ wc_.z); m3 += __popc(xc_.w ^ wc_.w);    \
            }                                                                \
        }                                                                    \
        const int mm_ = (m0 + m1) + (m2 + m3);                               \
        const int F_  = ((Wv) == 0) ? FL : (((Wv) == Wdim - 1) ? FR : FM);   \
        obuf[(pslot & 15) * 258 + tid] = sa_t * (float)(F_ - 2 * mm_);       \
        ++pslot;                                                             \
        if ((pslot & 15) == 0) {                                             \
            __syncthreads();                                                 \
            const int k_   = tid & 15;                                       \
            const int ch_  = tid >> 4;                                       \
            const int hwb_ = fcount << 4;                                    \
            _Pragma("unroll") for (int j_ = 0; j_ < 16; ++j_) {              \
                const int co_ = ch_ + 16 * j_;                               \
                out_b[(size_t)co_ * HW + hwb_ + k_] = obuf[k_ * 258 + co_];  \
            }                                                                \
            ++fcount;                                                        \
            __syncthreads();                                                 \
        }                                                                    \
    } while (0)

#pragma unroll 1
    for (int rr = 0; rr < 2; ++rr) {
        const int h  = h0 + rr;
        const int vp = (h == 0) ? 0 : ((h == Hdim - 1) ? 2 : 1);
        const int FL = (int)Ftab[(vp * 3 + 0) * 256 + tid];
        const int FM = (int)Ftab[(vp * 3 + 1) * 256 + tid];
        const int FR = (int)Ftab[(vp * 3 + 2) * 256 + tid];

        uint4 s0[6], s1[6], s2[6], s3[6];   // window: 4 cols x 3 rows x 4 words
        LOADSLOT(s0, 0); LOADSLOT(s1, 1); LOADSLOT(s2, 2); LOADSLOT(s3, 3);

#pragma unroll 1
        for (int wg = 0; wg < 14; ++wg) {
            const int w = wg * 4;
            COMPUTE(s0, s1, s2, w);     LOADSLOT(s0, w + 4);
            COMPUTE(s1, s2, s3, w + 1); LOADSLOT(s1, w + 5);
            COMPUTE(s2, s3, s0, w + 2); LOADSLOT(s2, w + 6);
            COMPUTE(s3, s0, s1, w + 3); LOADSLOT(s3, w + 7);
        }
    }
#undef COMPUTE
#undef LOADSLOT
}

extern "C" void kernel_launch(void* const* d_in, const int* in_sizes, int n_in,
                              void* d_out, int out_size, void* d_ws, size_t ws_size,
                              hipStream_t stream) {
    const float* x     = (const float*)d_in[0];   // [32,256,56,56]
    const float* wts   = (const float*)d_in[1];   // [4,256,256,3,3]
    const float* RV    = (const float*)d_in[2];   // [5]
    const float* alpha = (const float*)d_in[3];   // [256,1,1]
    float* out = (float*)d_out;                   // [32,256,56,56]

    uint8_t* ws = (uint8_t*)d_ws;
    uint32_t* wpack = (uint32_t*)(ws + OFF_WPACK);
    uint32_t* Ftab  = (uint32_t*)(ws + OFF_FTAB);
    float*    sa    = (float*)   (ws + OFF_SA);
    uint32_t* xbits = (uint32_t*)(ws + OFF_XBITS);

    prep_w_kernel<<<COUT, 256, 0, stream>>>(wts, RV, alpha, wpack, Ftab, sa);
    pack_x_kernel<<<NPIX / 256, 256, 0, stream>>>(x, xbits);
    conv_xnor_kernel<<<BATCH * 28, 256, 0, stream>>>(xbits, wpack, Ftab, sa, out);
}

// Round 5
// 173.886 us; speedup vs baseline: 1.8135x; 1.0026x over previous
//
#include <hip/hip_runtime.h>
#include <stdint.h>

// Problem constants (fixed by reference setup_inputs)
#define CIN   256
#define COUT  256
#define Hdim  56
#define Wdim  56
#define HW    3136        // 56*56
#define BATCH 32
#define NPIX  100352      // 32*3136
#define KREP  589824      // 256*256*9, stride between weight replicas
#define TAPS  9
#define WORDS 8           // 8 x uint32 = 256 channel bits

// ws layout (bytes) — IDENTICAL footprint to R1/R2/R4 (proven fit)
#define OFF_WPACK 0         // 256*72*4   = 73728
#define OFF_FTAB  73728     // 9*256*4    = 9216   (F = 256*ntap + 2*corr)
#define OFF_SA    82944     // 256*4      = 1024
#define OFF_XBITS 84224     // 100352*8*4 = 3211264 (unpadded [B][56][56][8])

// ---------------------------------------------------------------------------
// P1: real_w = sum_k RV[k]*W[k]; pack sign bits per (co, tap, word);
//     sa[co] = mean|real_w| * alpha[co];
//     Ftab[pattern][co] = 256*ntap + 2*corr (zero-pad-tap correction folded)
// (unchanged — verified since R1)
// ---------------------------------------------------------------------------
__global__ __launch_bounds__(256) void prep_w_kernel(
    const float* __restrict__ wts, const float* __restrict__ RV,
    const float* __restrict__ alpha, uint32_t* __restrict__ wpack,
    uint32_t* __restrict__ Ftab, float* __restrict__ sa)
{
    __shared__ uint32_t bits[TAPS * WORDS];
    __shared__ float    red[256];
    __shared__ int      pcw[TAPS];

    const int co = blockIdx.x;
    const int t  = threadIdx.x;

    if (t < TAPS * WORDS) bits[t] = 0u;
    __syncthreads();

    const float r0 = RV[0], r1 = RV[1], r2 = RV[2], r3 = RV[3];
    const float* base = wts + (size_t)co * 2304;

    float acc = 0.f;
#pragma unroll
    for (int j = 0; j < 9; ++j) {
        const int e = j * 256 + t;              // e = ci*9 + tap
        const float w0 = base[e];
        const float w1 = base[e + KREP];
        const float w2 = base[e + 2 * KREP];
        const float w3 = base[e + 3 * KREP];
        const float rw = r0 * w0 + r1 * w1 + r2 * w2 + r3 * w3;
        acc += fabsf(rw);
        const int ci  = e / 9;
        const int tap = e - ci * 9;
        if (rw < 0.f)
            atomicOr(&bits[tap * WORDS + (ci >> 5)], 1u << (ci & 31));
    }
    red[t] = acc;
    __syncthreads();

    for (int s = 128; s > 0; s >>= 1) {
        if (t < s) red[t] += red[t + s];
        __syncthreads();
    }

    if (t == 0) sa[co] = (red[0] * (1.0f / 2304.0f)) * alpha[co];
    if (t < TAPS * WORDS) wpack[co * 72 + t] = bits[t];
    if (t < TAPS) {
        int s = 0;
#pragma unroll
        for (int wd = 0; wd < WORDS; ++wd) s += __popc(bits[t * WORDS + wd]);
        pcw[t] = s;
    }
    __syncthreads();
    if (t < TAPS) {
        const int vp = t / 3, hp = t % 3;
        int c = 0;
#pragma unroll
        for (int kh = 0; kh < 3; ++kh)
#pragma unroll
            for (int kw = 0; kw < 3; ++kw) {
                const bool inv = (vp == 0 && kh == 0) || (vp == 2 && kh == 2) ||
                                 (hp == 0 && kw == 0) || (hp == 2 && kw == 2);
                if (inv) c += pcw[kh * 3 + kw];
            }
        const int ntap = ((vp == 1) ? 3 : 2) * ((hp == 1) ? 3 : 2);
        Ftab[t * 256 + co] = (uint32_t)(256 * ntap + 2 * c);
    }
}

// ---------------------------------------------------------------------------
// P2: binarize+pack x (unpadded [B][56][56][8]) — unchanged.
// ---------------------------------------------------------------------------
__global__ __launch_bounds__(256) void pack_x_kernel(
    const float* __restrict__ x, uint32_t* __restrict__ xbits)
{
    const int p  = blockIdx.x * 256 + threadIdx.x;   // pixel id < NPIX
    const int b  = p / HW;
    const int hw = p - b * HW;
    const float* xp = x + (size_t)b * CIN * HW + hw;

    uint32_t wv[WORDS];
#pragma unroll
    for (int j = 0; j < WORDS; ++j) {
        uint32_t m = 0;
#pragma unroll
        for (int bit = 0; bit < 32; ++bit) {
            const float v = xp[(size_t)(j * 32 + bit) * HW];
            m |= (__float_as_uint(v) >> 31) << bit;
        }
        wv[j] = m;
    }
    uint4* dst = (uint4*)(xbits + (size_t)p * WORDS);
    dst[0] = make_uint4(wv[0], wv[1], wv[2], wv[3]);
    dst[1] = make_uint4(wv[4], wv[5], wv[6], wv[7]);
}

// ---------------------------------------------------------------------------
// C: XNOR conv, lane-pair channel split. Block = 512 threads = 8 waves;
// wave wv covers co in [wv*32, wv*32+32): lane l and l^32 each own 4 of the
// 8 channel words (one uint4) of co = wv*32 + (l&31). Per-thread live set:
// 9 weight uint4 + 4-slot x window of 3 uint4 ~= 105 VGPRs (cap 128, no
// register shuffling). Each half writes its partial (half?0:sa*F)-2*sa*mm
// to obuf[pixel][2co+half]; flush adds pairs and stores coalesced.
// ---------------------------------------------------------------------------
__global__ __launch_bounds__(512, 4) void conv_xnor_kernel(
    const uint32_t* __restrict__ xbits, const uint32_t* __restrict__ wpack,
    const uint32_t* __restrict__ Ftab, const float* __restrict__ sa_g,
    float* __restrict__ out)
{
    __shared__ __align__(16) uint32_t xt[4 * 60 * WORDS];  // 7680 B
    __shared__ float obuf[16 * 520];                       // 33280 B

    const int tid  = threadIdx.x;
    const int lane = tid & 63;
    const int half = lane >> 5;                  // 0: words 0-3, 1: words 4-7
    const int co   = (tid >> 6) * 32 + (lane & 31);
    const int b    = blockIdx.x / 28;
    const int c    = blockIdx.x - b * 28;
    const int h0   = 2 * c;                      // first output row

    // weights: this half's uint4 per tap (9 x 4 VGPRs), resident
    uint4 wqv[9];
    {
        const uint4* wsrc = (const uint4*)wpack + (size_t)co * 18 + half;
#pragma unroll
        for (int t = 0; t < 9; ++t) wqv[t] = wsrc[t * 2];
    }
    const float sa_t = sa_g[co];
    const float m2sa = -2.0f * sa_t;

    // stage padded x tile: 4 rows x 60 cols x 8 words = 480 uint4
    {
        const uint4* srcb = (const uint4*)(xbits + (size_t)b * HW * WORDS);
        uint4* dst = (uint4*)xt;
        if (tid < 480) {
            const int tr  = tid / 120;
            const int u   = tid - tr * 120;
            const int col = u >> 1;              // padded col 0..59
            const int hr  = h0 - 1 + tr;         // real row
            uint4 v = make_uint4(0u, 0u, 0u, 0u);
            if (hr >= 0 && hr < Hdim && col >= 1 && col <= Wdim)
                v = srcb[((size_t)hr * Wdim + (col - 1)) * 2 + (u & 1)];
            dst[tid] = v;
        }
    }
    __syncthreads();

    const uint4* xt4 = (const uint4*)xt;
    float* out_b = out + (size_t)b * COUT * HW + (size_t)h0 * Wdim;

    int pslot  = 0;
    int fcount = 0;

#define LOADSLOT(S, C)                                                       \
    do {                                                                     \
        _Pragma("unroll") for (int r_ = 0; r_ < 3; ++r_)                     \
            (S)[r_] = xt4[(rr + r_) * 120 + (C) * 2 + half];                 \
    } while (0)

#define COMPUTE(SA, SB, SC, Wv)                                              \
    do {                                                                     \
        int m0 = 0, m1 = 0, m2 = 0, m3 = 0;                                  \
        _Pragma("unroll") for (int r_ = 0; r_ < 3; ++r_) {                   \
            const uint4 xa_ = (SA)[r_]; const uint4 wa_ = wqv[r_ * 3 + 0];   \
            m0 += __popc(xa_.x ^ wa_.x); m1 += __popc(xa_.y ^ wa_.y);        \
            m2 += __popc(xa_.z ^ wa_.z); m3 += __popc(xa_.w ^ wa_.w);        \
            const uint4 xb_ = (SB)[r_]; const uint4 wb_ = wqv[r_ * 3 + 1];   \
            m0 += __popc(xb_.x ^ wb_.x); m1 += __popc(xb_.y ^ wb_.y);        \
            m2 += __popc(xb_.z ^ wb_.z); m3 += __popc(xb_.w ^ wb_.w);        \
            const uint4 xc_ = (SC)[r_]; const uint4 wc_ = wqv[r_ * 3 + 2];   \
            m0 += __popc(xc_.x ^ wc_.x); m1 += __popc(xc_.y ^ wc_.y);        \
            m2 += __popc(xc_.z ^ wc_.z); m3 += __popc(xc_.w ^ wc_.w);        \
        }                                                                    \
        const int mm_ = (m0 + m1) + (m2 + m3);                               \
        const float sF_ =                                                    \
            ((Wv) == 0) ? sFL : (((Wv) == Wdim - 1) ? sFR : sFM);            \
        obuf[(pslot & 15) * 520 + co * 2 + half] =                           \
            fmaf(m2sa, (float)mm_, sF_);                                     \
        ++pslot;                                                             \
        if ((pslot & 15) == 0) {                                             \
            __syncthreads();                                                 \
            const int k_   = tid & 15;                                       \
            const int ch_  = tid >> 4;            /* 0..31 */                \
            const int hwb_ = fcount << 4;                                    \
            _Pragma("unroll") for (int j_ = 0; j_ < 8; ++j_) {               \
                const int co_ = ch_ + 32 * j_;                               \
                const float2 v_ =                                            \
                    *(const float2*)&obuf[k_ * 520 + co_ * 2];               \
                out_b[(size_t)co_ * HW + hwb_ + k_] = v_.x + v_.y;           \
            }                                                                \
            ++fcount;                                                        \
            __syncthreads();                                                 \
        }                                                                    \
    } while (0)

#pragma unroll 1
    for (int rr = 0; rr < 2; ++rr) {
        const int h  = h0 + rr;
        const int vp = (h == 0) ? 0 : ((h == Hdim - 1) ? 2 : 1);
        // half 0 carries the sa*F constant; half 1 contributes only -2sa*mm
        const float sFL = half ? 0.f : sa_t * (float)Ftab[(vp * 3 + 0) * 256 + co];
        const float sFM = half ? 0.f : sa_t * (float)Ftab[(vp * 3 + 1) * 256 + co];
        const float sFR = half ? 0.f : sa_t * (float)Ftab[(vp * 3 + 2) * 256 + co];

        uint4 s0[3], s1[3], s2[3], s3[3];   // 4-slot column window (this half)
        LOADSLOT(s0, 0); LOADSLOT(s1, 1); LOADSLOT(s2, 2); LOADSLOT(s3, 3);

#pragma unroll 1
        for (int wg = 0; wg < 14; ++wg) {
            const int w = wg * 4;
            COMPUTE(s0, s1, s2, w);     LOADSLOT(s0, w + 4);
            COMPUTE(s1, s2, s3, w + 1); LOADSLOT(s1, w + 5);
            COMPUTE(s2, s3, s0, w + 2); LOADSLOT(s2, w + 6);
            COMPUTE(s3, s0, s1, w + 3); LOADSLOT(s3, w + 7);
        }
    }
#undef COMPUTE
#undef LOADSLOT
}

extern "C" void kernel_launch(void* const* d_in, const int* in_sizes, int n_in,
                              void* d_out, int out_size, void* d_ws, size_t ws_size,
                              hipStream_t stream) {
    const float* x     = (const float*)d_in[0];   // [32,256,56,56]
    const float* wts   = (const float*)d_in[1];   // [4,256,256,3,3]
    const float* RV    = (const float*)d_in[2];   // [5]
    const float* alpha = (const float*)d_in[3];   // [256,1,1]
    float* out = (float*)d_out;                   // [32,256,56,56]

    uint8_t* ws = (uint8_t*)d_ws;
    uint32_t* wpack = (uint32_t*)(ws + OFF_WPACK);
    uint32_t* Ftab  = (uint32_t*)(ws + OFF_FTAB);
    float*    sa    = (float*)   (ws + OFF_SA);
    uint32_t* xbits = (uint32_t*)(ws + OFF_XBITS);

    prep_w_kernel<<<COUT, 256, 0, stream>>>(wts, RV, alpha, wpack, Ftab, sa);
    pack_x_kernel<<<NPIX / 256, 256, 0, stream>>>(x, xbits);
    conv_xnor_kernel<<<BATCH * 28, 512, 0, stream>>>(xbits, wpack, Ftab, sa, out);
}

// Round 7
// 149.939 us; speedup vs baseline: 2.1031x; 1.1597x over previous
//
#include <hip/hip_runtime.h>
#include <stdint.h>

// Problem constants (fixed by reference setup_inputs)
#define CIN   256
#define COUT  256
#define Hdim  56
#define Wdim  56
#define HW    3136        // 56*56
#define BATCH 32
#define NPIX  100352      // 32*3136
#define KREP  589824      // 256*256*9, stride between weight replicas
#define TAPS  9
#define WORDS 8           // 8 x uint32 = 256 channel bits

// ws layout (bytes) — total 3,286,016 <= R1-proven 3,295,488
#define OFF_WBT   0         // wbitsT: 9*2*256*8 ushorts = 73728 B
#define OFF_SA    73728     // 256*4 = 1024
#define OFF_XBITS 74752     // 100352*8*4 = 3211264 (unpadded [B][56][56][8])

typedef int int4v  __attribute__((ext_vector_type(4)));
typedef int int16v __attribute__((ext_vector_type(16)));

// 4 sign bits -> 4 int8 lanes of {-1,+1}. Byte-borrow-proof form:
// mask byte b in {0,1}; (0x81 - 2b) ^ 0x80 = {0x01, 0xFF} per byte, no borrow.
__device__ __forceinline__ uint32_t nib2pm1(uint32_t n) {
    const uint32_t mask = (n * 0x204081u) & 0x01010101u;
    return (0x81818181u - (mask << 1)) ^ 0x80808080u;
}

__device__ __forceinline__ int4v expand_pm1(uint32_t us) {
    int4v r;
    r.x = (int)nib2pm1(us & 15u);
    r.y = (int)nib2pm1((us >> 4) & 15u);
    r.z = (int)nib2pm1((us >> 8) & 15u);
    r.w = (int)nib2pm1((us >> 12) & 15u);
    return r;
}

__device__ __forceinline__ uint32_t ext16(const uint4 v, int c) {
    uint32_t comp = (c < 4) ? ((c < 2) ? v.x : v.y) : ((c < 6) ? v.z : v.w);
    return (c & 1) ? (comp >> 16) : (comp & 0xFFFFu);   // c static under unroll
}

// ---------------------------------------------------------------------------
// P1: real_w = sum_k RV[k]*W[k]; sa[co] = mean|real_w| * alpha[co];
//     pack sign bits into wbT[tap][g][co][c'] ushorts, where the ushort's
//     bit b corresponds to ci = c'*32 + g*16 + b of that tap.
// ---------------------------------------------------------------------------
__global__ __launch_bounds__(256) void prep_w_kernel(
    const float* __restrict__ wts, const float* __restrict__ RV,
    const float* __restrict__ alpha, unsigned short* __restrict__ wbT,
    float* __restrict__ sa)
{
    __shared__ uint32_t bits[TAPS * WORDS];   // bits[tap*8 + (ci>>5)]
    __shared__ float    red[256];

    const int co = blockIdx.x;
    const int t  = threadIdx.x;

    if (t < TAPS * WORDS) bits[t] = 0u;
    __syncthreads();

    const float r0 = RV[0], r1 = RV[1], r2 = RV[2], r3 = RV[3];
    const float* base = wts + (size_t)co * 2304;

    float acc = 0.f;
#pragma unroll
    for (int j = 0; j < 9; ++j) {
        const int e = j * 256 + t;              // e = ci*9 + tap
        const float w0 = base[e];
        const float w1 = base[e + KREP];
        const float w2 = base[e + 2 * KREP];
        const float w3 = base[e + 3 * KREP];
        const float rw = r0 * w0 + r1 * w1 + r2 * w2 + r3 * w3;
        acc += fabsf(rw);
        const int ci  = e / 9;
        const int tap = e - ci * 9;
        if (rw < 0.f)
            atomicOr(&bits[tap * WORDS + (ci >> 5)], 1u << (ci & 31));
    }
    red[t] = acc;
    __syncthreads();

    for (int s = 128; s > 0; s >>= 1) {
        if (t < s) red[t] += red[t + s];
        __syncthreads();
    }

    if (t == 0) sa[co] = (red[0] * (1.0f / 2304.0f)) * alpha[co];

    if (t < 144) {                       // 9 taps * 2 halves * 8 chunks
        const int tap = t >> 4;
        const int r   = t & 15;
        const int g   = r >> 3;          // ci 16-half
        const int c   = r & 7;           // ci 32-chunk
        const uint32_t v = (bits[tap * 8 + c] >> (g * 16)) & 0xFFFFu;
        wbT[(((tap * 2 + g) * 256 + co) << 3) + c] = (unsigned short)v;
    }
}

// ---------------------------------------------------------------------------
// P2: binarize+pack x (unpadded [B][56][56][8]) — unchanged, verified R1.
// ---------------------------------------------------------------------------
__global__ __launch_bounds__(256) void pack_x_kernel(
    const float* __restrict__ x, uint32_t* __restrict__ xbits)
{
    const int p  = blockIdx.x * 256 + threadIdx.x;   // pixel id < NPIX
    const int b  = p / HW;
    const int hw = p - b * HW;
    const float* xp = x + (size_t)b * CIN * HW + hw;

    uint32_t wv[WORDS];
#pragma unroll
    for (int j = 0; j < WORDS; ++j) {
        uint32_t m = 0;
#pragma unroll
        for (int bit = 0; bit < 32; ++bit) {
            const float v = xp[(size_t)(j * 32 + bit) * HW];
            m |= (__float_as_uint(v) >> 31) << bit;
        }
        wv[j] = m;
    }
    uint4* dst = (uint4*)(xbits + (size_t)p * WORDS);
    dst[0] = make_uint4(wv[0], wv[1], wv[2], wv[3]);
    dst[1] = make_uint4(wv[4], wv[5], wv[6], wv[7]);
}

// ---------------------------------------------------------------------------
// C: implicit-GEMM XNOR conv on the i8 matrix pipe.
// Block = 512 thr = 8 waves (2 M-groups x 4 N-groups), M-tile 128 px
// (25th tile per image is a 64-px half tile), N-tile 256 co.
// x staged once per block in LDS as +/-1 int8 (pad=0), granule-XOR-swizzled.
// W stays bit-packed (74 KB, L2-resident), expanded to +/-1 per k-step.
// out = sa[co] * acc  (no border table needed: pad contributes exactly 0).
// ---------------------------------------------------------------------------
__global__ __launch_bounds__(512, 2) void conv_mfma_kernel(
    const uint32_t* __restrict__ xbits, const unsigned short* __restrict__ wbT,
    const float* __restrict__ sa_g, float* __restrict__ out)
{
    __shared__ __align__(16) int xt[348 * 64];  // 6 rows x 58 cols x 256 i8

    const int tid  = threadIdx.x;
    const int lane = tid & 63;
    const int half = lane >> 5;
    const int l31  = lane & 31;
    const int wid  = tid >> 6;
    const int mg   = wid >> 2;       // M-group 0..1
    const int ng   = wid & 3;        // N-group 0..3

    const int blk = blockIdx.x;
    const int b   = blk / 25;
    const int T   = blk - b * 25;
    const int p0  = T * 128;
    const bool full = (T < 24);
    const int mgE = full ? mg : 0;   // half tile: both M-groups mirror mg=0
    const int h0  = p0 / 56;

    // ---- stage + expand x tile (rows h0-1 .. h0+4, cols -1..56, pad = 0)
    {
        const uint32_t* xb = xbits + (size_t)b * (HW * WORDS);
        for (int u = tid; u < 348 * 32; u += 512) {   // b64 units
            const int cell = u >> 5, p = u & 31;
            const int row = cell / 58;
            const int col = cell - row * 58;
            const int hh = h0 - 1 + row, ww = col - 1;
            const bool ok = (hh >= 0) && (hh < Hdim) && (ww >= 0) && (ww < Wdim);
            uint32_t byteval = 0;
            if (ok)
                byteval = (xb[((hh * 56 + ww) << 3) + (p >> 2)] >> ((p & 3) * 8)) & 0xFFu;
            uint32_t d0 = nib2pm1(byteval & 15u);
            uint32_t d1 = nib2pm1(byteval >> 4);
            if (!ok) { d0 = 0u; d1 = 0u; }            // pad contributes 0
            const int f   = (col + 2 * row) & 15;
            const int idx = cell * 64 + (((p >> 1) ^ f) << 2) + ((p & 1) << 1);
            *reinterpret_cast<uint2*>(&xt[idx]) = make_uint2(d0, d1);
        }
    }
    __syncthreads();

    // ---- per-lane geometry
    const int px0 = p0 + mgE * 64 + l31;      // m-frag 0
    const int px1 = px0 + 32;                 // m-frag 1
    const int h_0 = px0 / 56, w_0 = px0 - h_0 * 56;
    const int h_1 = px1 / 56, w_1 = px1 - h_1 * 56;
    const int rb0 = h_0 - h0, rb1 = h_1 - h0;

    const int co0 = ng * 64 + l31;
    const int co1 = co0 + 32;
    const float s0 = sa_g[co0], s1 = sa_g[co1];

    const unsigned short* wp0 = wbT + (((half << 8) + co0) << 3);
    const unsigned short* wp1 = wbT + (((half << 8) + co1) << 3);
    // tap stride in ushorts = 2*256*8 = 4096

    int16v a00 = {0,0,0,0,0,0,0,0,0,0,0,0,0,0,0,0};
    int16v a01 = {0,0,0,0,0,0,0,0,0,0,0,0,0,0,0,0};
    int16v a10 = {0,0,0,0,0,0,0,0,0,0,0,0,0,0,0,0};
    int16v a11 = {0,0,0,0,0,0,0,0,0,0,0,0,0,0,0,0};

    uint4 wb0 = *(const uint4*)wp0;
    uint4 wb1 = *(const uint4*)wp1;

#pragma unroll 1
    for (int t = 0; t < 9; ++t) {
        const int tn = (t < 8) ? (t + 1) : 8;          // safe dummy prefetch
        const uint4 wb0n = *(const uint4*)(wp0 + tn * 4096);
        const uint4 wb1n = *(const uint4*)(wp1 + tn * 4096);

        const int kh = (t * 11) >> 5;                  // t/3 for t<9
        const int kw = t - kh * 3;
        const int cb0 = ((rb0 + kh) * 58 + w_0 + kw) * 64;
        const int f0  = (w_0 + kw + 2 * (rb0 + kh)) & 15;
        const int cb1 = ((rb1 + kh) * 58 + w_1 + kw) * 64;
        const int f1  = (w_1 + kw + 2 * (rb1 + kh)) & 15;

#pragma unroll
        for (int c = 0; c < 8; ++c) {
            const int g0 = ((((c << 1) | half) ^ f0) << 2);
            const int g1 = ((((c << 1) | half) ^ f1) << 2);
            const int4v av0 = *(const int4v*)&xt[cb0 + g0];
            const int4v av1 = *(const int4v*)&xt[cb1 + g1];
            const int4v bv0 = expand_pm1(ext16(wb0, c));
            const int4v bv1 = expand_pm1(ext16(wb1, c));
            a00 = __builtin_amdgcn_mfma_i32_32x32x32_i8(av0, bv0, a00, 0, 0, 0);
            a01 = __builtin_amdgcn_mfma_i32_32x32x32_i8(av0, bv1, a01, 0, 0, 0);
            a10 = __builtin_amdgcn_mfma_i32_32x32x32_i8(av1, bv0, a10, 0, 0, 0);
            a11 = __builtin_amdgcn_mfma_i32_32x32x32_i8(av1, bv1, a11, 0, 0, 0);
        }
        wb0 = wb0n; wb1 = wb1n;
    }

    // ---- epilogue: out[b][co][px] = sa[co] * acc
    if (full || mg == 0) {
        float* ob = out + (size_t)b * (COUT * HW);
        const int pxb = p0 + mgE * 64;
#pragma unroll
        for (int reg = 0; reg < 16; ++reg) {
            const int row = (reg & 3) + ((reg >> 2) << 3) + (half << 2);
            ob[(size_t)co0 * HW + pxb + row]      = s0 * (float)a00[reg];
            ob[(size_t)co1 * HW + pxb + row]      = s1 * (float)a01[reg];
            ob[(size_t)co0 * HW + pxb + 32 + row] = s0 * (float)a10[reg];
            ob[(size_t)co1 * HW + pxb + 32 + row] = s1 * (float)a11[reg];
        }
    }
}

extern "C" void kernel_launch(void* const* d_in, const int* in_sizes, int n_in,
                              void* d_out, int out_size, void* d_ws, size_t ws_size,
                              hipStream_t stream) {
    const float* x     = (const float*)d_in[0];   // [32,256,56,56]
    const float* wts   = (const float*)d_in[1];   // [4,256,256,3,3]
    const float* RV    = (const float*)d_in[2];   // [5]
    const float* alpha = (const float*)d_in[3];   // [256,1,1]
    float* out = (float*)d_out;                   // [32,256,56,56]

    uint8_t* ws = (uint8_t*)d_ws;
    unsigned short* wbT = (unsigned short*)(ws + OFF_WBT);
    float*    sa    = (float*)   (ws + OFF_SA);
    uint32_t* xbits = (uint32_t*)(ws + OFF_XBITS);

    prep_w_kernel<<<COUT, 256, 0, stream>>>(wts, RV, alpha, wbT, sa);
    pack_x_kernel<<<NPIX / 256, 256, 0, stream>>>(x, xbits);
    conv_mfma_kernel<<<BATCH * 25, 512, 0, stream>>>(xbits, wbT, sa, out);
}